// Round 13
// baseline (268.763 us; speedup 1.0000x reference)
//
#include <hip/hip_runtime.h>
#include <math.h>

// ============================================================================
// Sizes (fixed): N=2, C=64, Hax=56, W=56 -> B=112, H=56, OUT=64, N_HASHES=4,
// CHUNK=25, GROUPS=8, GP=8, hash_buckets=2, padding=19, K=3, qkv ch=96.
// Inputs fp32; OUTPUT FP32; stable argsort (established R8-R11).
// R12: 181 us total, k3=59.6 us (LDS-pipe bound: 84B/j/lane), k12 ~30 us
// (scalar-LDS GEMM). R13: k3 LDS diet (VE/WE via L1, rawWb k-only -> 39.6KB
// LDS -> 4 blocks/CU, reg-cached DI phase, DI float4) + k12 reg-tiled GEMM.
//
// ws layout (float slots):
//   qkv : [112][5376]   off 0
//   bsb : [112][2400]   off 602112
//   Rb  : [112][38400]  off 870912
//   idx : [112][224]    off 5171712  (int)
// ============================================================================

#define EPSN 5e-5f
#define LOG2E 1.4426950408889634f
#define LN2   0.6931471805599453f

__device__ __forceinline__ float dot4(const float4 a, const float4 b) {
    return a.x * b.x + a.y * b.y + a.z * b.z + a.w * b.w;
}
__device__ __forceinline__ void fma4(float4& a, float s, const float4 v) {
    a.x += s * v.x; a.y += s * v.y; a.z += s * v.z; a.w += s * v.w;
}

// ---------------- K12: qkv GEMM (reg-tiled) + BN + LSH codes + stable sort ----
__global__ __launch_bounds__(256) void k12_qkv_sort(
        const float* __restrict__ x, const float* __restrict__ cw,
        const float* __restrict__ gamma, const float* __restrict__ beta,
        const float* __restrict__ rot, float* __restrict__ qkv,
        int* __restrict__ idx_buf) {
    __shared__ float xsT[56 * 68];   // [h][c], padded 64->68 (16B align + banks)
    __shared__ float cws[96 * 64];
    __shared__ float wm[56 * 32];    // w_match[t][f]
    __shared__ float rl[128];
    __shared__ float gs[96], bt[96];
    __shared__ int code[224];
    __shared__ int srt[224];
    const int b = blockIdx.x, n = b / 56, w = b % 56, tid = threadIdx.x;
    const float* xb = x + n * 200704 + w;
    for (int i = tid; i < 3584; i += 256) {
        int c = i / 56, h = i % 56;
        xsT[h * 68 + c] = xb[c * 3136 + h * 56];
    }
    for (int i = tid; i < 6144; i += 256) cws[i] = cw[i];
    if (tid < 128) rl[tid] = rot[tid];
    if (tid < 96) { gs[tid] = gamma[tid]; bt[tid] = beta[tid]; }
    __syncthreads();
    const float inv_s = 1.0f / sqrtf(1.0f + 1.0e-5f);
    if (tid < 224) {                       // h = lane-ish, 24-wide o register tile
        const int h = tid % 56, o0 = (tid / 56) * 24;
        float acc[24];
        #pragma unroll
        for (int oo = 0; oo < 24; ++oo) acc[oo] = 0.f;
        #pragma unroll
        for (int cs = 0; cs < 16; ++cs) {
            float4 xv = *(const float4*)&xsT[h * 68 + cs * 4];
            #pragma unroll
            for (int oo = 0; oo < 24; ++oo) {
                float4 cv = *(const float4*)&cws[(o0 + oo) * 64 + cs * 4];
                acc[oo] += dot4(xv, cv);   // cws addr wave-uniform -> broadcast
            }
        }
        #pragma unroll
        for (int oo = 0; oo < 24; ++oo) {
            int o = o0 + oo;
            float val = acc[oo] * inv_s * gs[o] + bt[o];
            qkv[b * 5376 + o * 56 + h] = val;   // coalesced over h
            int t96 = o * 56 + h, f = t96 % 96; // raw (B,96,56)->(B,56,96) reshape
            if (f < 32) wm[(t96 / 96) * 32 + f] = val;
        }
    }
    __syncthreads();
    if (tid < 224) {
        int u = tid / 56, t = tid % 56;
        float s = 0.f;
        #pragma unroll 8
        for (int f = 0; f < 32; ++f) s += wm[t * 32 + f] * rl[f * 4 + u];
        code[tid] = ((s < 0.f) ? 1 : 0) + 2 * u; // argmax([s,-s]) + u*hash_buckets
    }
    __syncthreads();
    if (tid < 224) {
        int c = code[tid], r = 0;
        for (int p = 0; p < 224; ++p) {
            int cp = code[p];
            r += (int)((cp < c) | ((cp == c) & (p < tid)));  // stable rank
        }
        srt[r] = tid;
    }
    __syncthreads();
    if (tid < 224) idx_buf[b * 224 + tid] = srt[tid];
}

// ---------------- K3: chunked attention, one block per (b,u,k) ----------------
// LDS 39.6KB -> 4 blocks/CU. VE/WE read from rel (L1) in-loop, not LDS.
__global__ __launch_bounds__(256) void k3_attn(
        const float* __restrict__ qkv, const int* __restrict__ idx_buf,
        const float* __restrict__ rel, float* __restrict__ Rb,
        float* __restrict__ bsb) {
    __shared__ __align__(16) float WbK[8][25][4];     // raw w_b at kk==k only
    __shared__ __align__(16) float Wc [8][3][25][4];  // normalized, then +0.1*WE
    __shared__ __align__(16) float Vb [8][3][25][8];
    __shared__ float DI[25][76];
    const int b = blockIdx.x, u = blockIdx.y, k = blockIdx.z;
    const int tid = threadIdx.x;
    const int km1 = (k + 2) % 3, kp1 = (k + 1) % 3;
    const float* q = qkv + b * 5376;
    const int* ib = idx_buf + b * 224;

    // Wb gather + normalize-on-load (fragment = 4 contiguous floats in qkv)
    for (int idx = tid; idx < 600; idx += 256) {
        int i = idx % 25, kk = (idx / 25) % 3, g = idx / 75;
        int p0 = 1200 * g + 300 * u + 100 * kk + 4 * i;
        int h = p0 / 2400, r = p0 % 2400, t = r >> 5, f = r & 31;
        int row = (t < 56) ? t : t - 19;
        int tt = ib[h * 56 + row] % 56;
        float4 v = *(const float4*)&q[tt * 96 + f];
        float ni = 1.0f / fmaxf(sqrtf(dot4(v, v)), EPSN);
        float4 vn = v;
        vn.x *= ni; vn.y *= ni; vn.z *= ni; vn.w *= ni;
        *(float4*)&Wc[g][kk][i][0] = vn;
        if (kk == k) *(float4*)&WbK[g][i][0] = v;
    }
    // Vb gather: 8 contiguous floats per fragment (2 float4 halves)
    for (int idx = tid; idx < 1200; idx += 256) {
        int half = idx & 1, fr = idx >> 1;
        int i = fr % 25, kk = (fr / 25) % 3, g = fr / 75;
        int p0 = 2400 * g + 600 * u + 200 * kk + 8 * i + 4 * half;
        int h = p0 / 4800, r = p0 % 4800, t = r >> 6, f = r & 63;
        int row = (t < 56) ? t : t - 19;
        int tt = ib[h * 56 + row] % 56;
        *(float4*)&Vb[g][kk][i][4 * half] = *(const float4*)&q[tt * 96 + 32 + f];
    }
    __syncthreads();
    // DI phase: thread-fixed i, 8 wb fragments cached in registers
    if (tid < 250) {
        const int i = tid % 25, jg = tid / 25;
        float4 wb8[8];
        #pragma unroll
        for (int g = 0; g < 8; ++g) wb8[g] = *(const float4*)&WbK[g][i][0];
        #pragma unroll
        for (int it = 0; it < 8; ++it) {
            int j = jg * 8 + it;
            if (j >= 75) break;
            int jb = j / 25, jj = j % 25;
            int ks = (jb == 0) ? k : ((jb == 1) ? km1 : kp1);
            int tw = ks * 25 + jj;
            int roww = (tw < 56) ? tw : tw - 19;
            float4 we = *(const float4*)&rel[roww * 12];      // L1-resident
            we.x *= 0.1f; we.y *= 0.1f; we.z *= 0.1f; we.w *= 0.1f;
            float s2 = 0.f;
            #pragma unroll
            for (int g = 0; g < 8; ++g) {
                float4 wbn = *(const float4*)&Wc[g][ks][jj][0];
                float raw = dot4(wb8[g], wbn);
                float emb = dot4(wb8[g], we);
                s2 += raw * raw + emb * emb;
            }
            DI[i][j] = 1.0f / fmaxf(sqrtf(s2), EPSN);
        }
    }
    const int g = tid & 7, i = tid >> 3;
    float4 wbr;
    if (tid < 200) wbr = *(const float4*)&WbK[g][i][0];
    __syncthreads();
    // fold: Wc = WbN + 0.1*WE (WE from rel, L1)
    for (int idx = tid; idx < 600; idx += 256) {
        int i2 = idx % 25, kk = (idx / 25) % 3, g2 = idx / 75;
        int t = kk * 25 + i2; int row = (t < 56) ? t : t - 19;
        float4 we = *(const float4*)&rel[row * 12];
        float4 v = *(const float4*)&Wc[g2][kk][i2][0];
        v.x += 0.1f * we.x; v.y += 0.1f * we.y;
        v.z += 0.1f * we.z; v.w += 0.1f * we.w;
        *(float4*)&Wc[g2][kk][i2][0] = v;
    }
    __syncthreads();
    // softmax + PV, one thread per (g,i)
    if (tid < 200) {
        float ssv[75];
        float m = -INFINITY;
        float4 d4;
        #pragma unroll
        for (int j = 0; j < 75; ++j) {
            int jb = j / 25, jj = j % 25;
            int ks = (jb == 0) ? k : ((jb == 1) ? km1 : kp1);
            if ((j & 3) == 0) d4 = *(const float4*)&DI[i][j];
            float di = (j & 3) == 0 ? d4.x : ((j & 3) == 1 ? d4.y : ((j & 3) == 2 ? d4.z : d4.w));
            float v = dot4(wbr, *(const float4*)&Wc[g][ks][jj][0]) * di;
            ssv[j] = v;
            m = fmaxf(m, v);
        }
        float se = 0.f;
        float4 a0 = {0,0,0,0}, a1 = {0,0,0,0}, a2 = {0,0,0,0}, a3 = {0,0,0,0};
        const float mm = m * LOG2E;
        #pragma unroll
        for (int j = 0; j < 75; ++j) {
            int jb = j / 25, jj = j % 25;
            int ks = (jb == 0) ? k : ((jb == 1) ? km1 : kp1);
            float e = __builtin_amdgcn_exp2f(ssv[j] * LOG2E - mm);
            se += e;
            const float4* vv = (const float4*)&Vb[g][ks][jj][0];
            fma4(a0, e, vv[0]); fma4(a1, e, vv[1]);
            int tw = ks * 25 + jj;
            int roww = (tw < 56) ? tw : tw - 19;
            float4 ve0 = *(const float4*)&rel[roww * 12 + 4];  // L1-resident
            float4 ve1 = *(const float4*)&rel[roww * 12 + 8];
            fma4(a2, e, ve0); fma4(a3, e, ve1);
        }
        bsb[b * 2400 + g * 300 + u * 75 + k * 25 + i] =
            m + __builtin_amdgcn_logf(se) * LN2;
        const float rinv = 1.0f / se;
        const float r2 = 0.1f * rinv;            // F_GV1
        a0.x *= rinv; a0.y *= rinv; a0.z *= rinv; a0.w *= rinv;
        a1.x *= rinv; a1.y *= rinv; a1.z *= rinv; a1.w *= rinv;
        a2.x *= r2;   a2.y *= r2;   a2.z *= r2;   a2.w *= r2;
        a3.x *= r2;   a3.y *= r2;   a3.z *= r2;   a3.w *= r2;
        float* rp = Rb + b * 38400 + 4800 * g + 1200 * u + 400 * k + 16 * i;
        ((float4*)rp)[0] = a0;
        ((float4*)rp)[1] = a1;
        ((float4*)rp)[2] = a2;
        ((float4*)rp)[3] = a3;
    }
}

// ---------------- K45: channel l2norm + pair-sum + unsort + hash softmax
//                        + transposed FP32 store ----------------
__global__ __launch_bounds__(256) void k45_post(
        const float* __restrict__ Rb, const float* __restrict__ bsb,
        const int* __restrict__ idx_buf, float* __restrict__ out) {
    __shared__ float D[300];
    __shared__ float bsn[300];
    __shared__ float retU[224][64];
    __shared__ float bsU[224];
    __shared__ int idxL[224];
    const int b = blockIdx.x, tid = threadIdx.x;
    const int n = b / 56, w = b % 56;
    const float* R = Rb + b * 38400;
    if (tid < 224) idxL[tid] = idx_buf[b * 224 + tid];
    for (int r = tid; r < 300; r += 256) {
        float s = 0.f;
        for (int c = 0; c < 128; ++c) { float v = R[c * 300 + r]; s += v * v; }
        D[r] = fmaxf(sqrtf(s), EPSN);
    }
    for (int idx = tid; idx < 300; idx += 256) {
        int u = idx / 75, t = idx % 75;
        float s2 = 0.f, sum = 0.f;
        #pragma unroll
        for (int g = 0; g < 8; ++g) {
            float v = bsb[b * 2400 + g * 300 + u * 75 + t];
            s2 += v * v; sum += v;
        }
        bsn[idx] = sum / fmaxf(sqrtf(s2), EPSN);
    }
    __syncthreads();
    for (int idx = tid; idx < 224 * 64; idx += 256) {
        int p = idx >> 6, o = idx & 63;
        int u3 = p / 56, t = p % 56;
        int k3 = t / 25, i3 = t % 25;
        int q0 = 9600 * u3 + 3200 * k3 + 128 * i3 + 2 * o;
        float2 rv = *(const float2*)&R[q0];
        float val = rv.x / D[q0 % 300] + rv.y / D[(q0 + 1) % 300];
        int r = idxL[p];
        retU[r][o] = val;
        if (o == 0) bsU[r] = bsn[u3 * 75 + t];
    }
    __syncthreads();
    for (int idx = tid; idx < 56 * 64; idx += 256) {
        int h = idx >> 6, o = idx & 63;
        float b0 = bsU[h], b1 = bsU[56 + h], b2 = bsU[112 + h], b3 = bsU[168 + h];
        float m = fmaxf(fmaxf(b0, b1), fmaxf(b2, b3));
        float e0 = __builtin_amdgcn_exp2f((b0 - m) * LOG2E);
        float e1 = __builtin_amdgcn_exp2f((b1 - m) * LOG2E);
        float e2 = __builtin_amdgcn_exp2f((b2 - m) * LOG2E);
        float e3 = __builtin_amdgcn_exp2f((b3 - m) * LOG2E);
        float ps = e0 + e1 + e2 + e3;
        float val = (retU[h][o] * e0 + retU[56 + h][o] * e1 +
                     retU[112 + h][o] * e2 + retU[168 + h][o] * e3) / ps;
        out[((n * 64 + o) * 56 + h) * 56 + w] = val;   // (n,o,h,w)
    }
}

extern "C" void kernel_launch(void* const* d_in, const int* in_sizes, int n_in,
                              void* d_out, int out_size, void* d_ws, size_t ws_size,
                              hipStream_t stream) {
    (void)in_sizes; (void)n_in; (void)out_size; (void)ws_size;
    const float* x     = (const float*)d_in[0];
    const float* cw    = (const float*)d_in[1];
    const float* gamma = (const float*)d_in[2];
    const float* beta  = (const float*)d_in[3];
    const float* rel   = (const float*)d_in[4];
    const float* rot   = (const float*)d_in[5];
    float* ws  = (float*)d_ws;
    float* qkv = ws;
    float* bsb = ws + 602112;
    float* Rb  = ws + 870912;
    int*   idx = (int*)(ws + 5171712);

    k12_qkv_sort<<<112, 256, 0, stream>>>(x, cw, gamma, beta, rot, qkv, idx);
    k3_attn<<<dim3(112, 4, 3), 256, 0, stream>>>(qkv, idx, rel, Rb, bsb);
    k45_post<<<112, 256, 0, stream>>>(Rb, bsb, idx, (float*)d_out);
}

// Round 14
// 169.516 us; speedup vs baseline: 1.5855x; 1.5855x over previous
//
#include <hip/hip_runtime.h>
#include <math.h>

// ============================================================================
// Sizes (fixed): N=2, C=64, Hax=56, W=56 -> B=112, H=56, OUT=64, N_HASHES=4,
// CHUNK=25, GROUPS=8, GP=8, hash_buckets=2, padding=19, K=3, qkv ch=96.
// Inputs fp32; OUTPUT FP32; stable argsort (established R8-R11).
// R12: 181 us (k3=59.6). R13: k12 24-wide reg tile SPILLED (VGPR=256,
// 104MB scratch writes, 125 us) -> 269 us total. R14: k12 back to
// 1-output/iter j-loop but with float4 LDS reads (xsT[h][c] pad 68 + cws
// float4, ~10 live VGPRs, no spill). k3/k45 unchanged from R13 (measure k3).
//
// ws layout (float slots):
//   qkv : [112][5376]   off 0
//   bsb : [112][2400]   off 602112
//   Rb  : [112][38400]  off 870912
//   idx : [112][224]    off 5171712  (int)
// ============================================================================

#define EPSN 5e-5f
#define LOG2E 1.4426950408889634f
#define LN2   0.6931471805599453f

__device__ __forceinline__ float dot4(const float4 a, const float4 b) {
    return a.x * b.x + a.y * b.y + a.z * b.z + a.w * b.w;
}
__device__ __forceinline__ void fma4(float4& a, float s, const float4 v) {
    a.x += s * v.x; a.y += s * v.y; a.z += s * v.z; a.w += s * v.w;
}

// ---------------- K12: qkv GEMM + BN + LSH codes + stable argsort ----------------
// 1 output per thread-iteration (no reg tile -> no spill); float4 LDS reads.
__global__ __launch_bounds__(256) void k12_qkv_sort(
        const float* __restrict__ x, const float* __restrict__ cw,
        const float* __restrict__ gamma, const float* __restrict__ beta,
        const float* __restrict__ rot, float* __restrict__ qkv,
        int* __restrict__ idx_buf) {
    __shared__ float xsT[56 * 68];   // [h][c], pad 64->68 (16B-aligned rows, odd f4 stride)
    __shared__ float cws[96 * 64];
    __shared__ float wm[56 * 32];    // w_match[t][f]
    __shared__ float rl[128];
    __shared__ float gs[96], bt[96];
    __shared__ int code[224];
    __shared__ int srt[224];
    const int b = blockIdx.x, n = b / 56, w = b % 56, tid = threadIdx.x;
    const float* xb = x + n * 200704 + w;
    for (int i = tid; i < 3584; i += 256) {
        int c = i / 56, h = i % 56;
        xsT[h * 68 + c] = xb[c * 3136 + h * 56];
    }
    for (int i = tid; i < 6144; i += 256) cws[i] = cw[i];
    if (tid < 128) rl[tid] = rot[tid];
    if (tid < 96) { gs[tid] = gamma[tid]; bt[tid] = beta[tid]; }
    __syncthreads();
    const float inv_s = 1.0f / sqrtf(1.0f + 1.0e-5f);
    for (int j = tid; j < 5376; j += 256) {      // j = o*56 + h
        int o = j / 56, h = j % 56;
        float s = 0.f;
        #pragma unroll
        for (int cs = 0; cs < 16; ++cs) {
            float4 xv = *(const float4*)&xsT[h * 68 + cs * 4];
            float4 cv = *(const float4*)&cws[o * 64 + cs * 4];
            s += dot4(xv, cv);
        }
        float val = s * inv_s * gs[o] + bt[o];
        qkv[b * 5376 + j] = val;
        int f = j % 96;                          // raw (B,96,56)->(B,56,96) reshape
        if (f < 32) wm[(j / 96) * 32 + f] = val;
    }
    __syncthreads();
    if (tid < 224) {
        int u = tid / 56, t = tid % 56;
        float s = 0.f;
        #pragma unroll 8
        for (int f = 0; f < 32; ++f) s += wm[t * 32 + f] * rl[f * 4 + u];
        code[tid] = ((s < 0.f) ? 1 : 0) + 2 * u; // argmax([s,-s]) + u*hash_buckets
    }
    __syncthreads();
    if (tid < 224) {
        int c = code[tid], r = 0;
        for (int p = 0; p < 224; ++p) {
            int cp = code[p];
            r += (int)((cp < c) | ((cp == c) & (p < tid)));  // stable rank
        }
        srt[r] = tid;
    }
    __syncthreads();
    if (tid < 224) idx_buf[b * 224 + tid] = srt[tid];
}

// ---------------- K3: chunked attention, one block per (b,u,k) ----------------
// LDS 39.6KB -> 4 blocks/CU. VE/WE read from rel (L1) in-loop, not LDS.
__global__ __launch_bounds__(256) void k3_attn(
        const float* __restrict__ qkv, const int* __restrict__ idx_buf,
        const float* __restrict__ rel, float* __restrict__ Rb,
        float* __restrict__ bsb) {
    __shared__ __align__(16) float WbK[8][25][4];     // raw w_b at kk==k only
    __shared__ __align__(16) float Wc [8][3][25][4];  // normalized, then +0.1*WE
    __shared__ __align__(16) float Vb [8][3][25][8];
    __shared__ float DI[25][76];
    const int b = blockIdx.x, u = blockIdx.y, k = blockIdx.z;
    const int tid = threadIdx.x;
    const int km1 = (k + 2) % 3, kp1 = (k + 1) % 3;
    const float* q = qkv + b * 5376;
    const int* ib = idx_buf + b * 224;

    for (int idx = tid; idx < 600; idx += 256) {
        int i = idx % 25, kk = (idx / 25) % 3, g = idx / 75;
        int p0 = 1200 * g + 300 * u + 100 * kk + 4 * i;
        int h = p0 / 2400, r = p0 % 2400, t = r >> 5, f = r & 31;
        int row = (t < 56) ? t : t - 19;
        int tt = ib[h * 56 + row] % 56;
        float4 v = *(const float4*)&q[tt * 96 + f];
        float ni = 1.0f / fmaxf(sqrtf(dot4(v, v)), EPSN);
        float4 vn = v;
        vn.x *= ni; vn.y *= ni; vn.z *= ni; vn.w *= ni;
        *(float4*)&Wc[g][kk][i][0] = vn;
        if (kk == k) *(float4*)&WbK[g][i][0] = v;
    }
    for (int idx = tid; idx < 1200; idx += 256) {
        int half = idx & 1, fr = idx >> 1;
        int i = fr % 25, kk = (fr / 25) % 3, g = fr / 75;
        int p0 = 2400 * g + 600 * u + 200 * kk + 8 * i + 4 * half;
        int h = p0 / 4800, r = p0 % 4800, t = r >> 6, f = r & 63;
        int row = (t < 56) ? t : t - 19;
        int tt = ib[h * 56 + row] % 56;
        *(float4*)&Vb[g][kk][i][4 * half] = *(const float4*)&q[tt * 96 + 32 + f];
    }
    __syncthreads();
    if (tid < 250) {
        const int i = tid % 25, jg = tid / 25;
        float4 wb8[8];
        #pragma unroll
        for (int g = 0; g < 8; ++g) wb8[g] = *(const float4*)&WbK[g][i][0];
        #pragma unroll
        for (int it = 0; it < 8; ++it) {
            int j = jg * 8 + it;
            if (j >= 75) break;
            int jb = j / 25, jj = j % 25;
            int ks = (jb == 0) ? k : ((jb == 1) ? km1 : kp1);
            int tw = ks * 25 + jj;
            int roww = (tw < 56) ? tw : tw - 19;
            float4 we = *(const float4*)&rel[roww * 12];      // L1-resident
            we.x *= 0.1f; we.y *= 0.1f; we.z *= 0.1f; we.w *= 0.1f;
            float s2 = 0.f;
            #pragma unroll
            for (int g = 0; g < 8; ++g) {
                float4 wbn = *(const float4*)&Wc[g][ks][jj][0];
                float raw = dot4(wb8[g], wbn);
                float emb = dot4(wb8[g], we);
                s2 += raw * raw + emb * emb;
            }
            DI[i][j] = 1.0f / fmaxf(sqrtf(s2), EPSN);
        }
    }
    const int g = tid & 7, i = tid >> 3;
    float4 wbr;
    if (tid < 200) wbr = *(const float4*)&WbK[g][i][0];
    __syncthreads();
    for (int idx = tid; idx < 600; idx += 256) {
        int i2 = idx % 25, kk = (idx / 25) % 3, g2 = idx / 75;
        int t = kk * 25 + i2; int row = (t < 56) ? t : t - 19;
        float4 we = *(const float4*)&rel[row * 12];
        float4 v = *(const float4*)&Wc[g2][kk][i2][0];
        v.x += 0.1f * we.x; v.y += 0.1f * we.y;
        v.z += 0.1f * we.z; v.w += 0.1f * we.w;
        *(float4*)&Wc[g2][kk][i2][0] = v;
    }
    __syncthreads();
    if (tid < 200) {
        float ssv[75];
        float m = -INFINITY;
        float4 d4;
        #pragma unroll
        for (int j = 0; j < 75; ++j) {
            int jb = j / 25, jj = j % 25;
            int ks = (jb == 0) ? k : ((jb == 1) ? km1 : kp1);
            if ((j & 3) == 0) d4 = *(const float4*)&DI[i][j];
            float di = (j & 3) == 0 ? d4.x : ((j & 3) == 1 ? d4.y : ((j & 3) == 2 ? d4.z : d4.w));
            float v = dot4(wbr, *(const float4*)&Wc[g][ks][jj][0]) * di;
            ssv[j] = v;
            m = fmaxf(m, v);
        }
        float se = 0.f;
        float4 a0 = {0,0,0,0}, a1 = {0,0,0,0}, a2 = {0,0,0,0}, a3 = {0,0,0,0};
        const float mm = m * LOG2E;
        #pragma unroll
        for (int j = 0; j < 75; ++j) {
            int jb = j / 25, jj = j % 25;
            int ks = (jb == 0) ? k : ((jb == 1) ? km1 : kp1);
            float e = __builtin_amdgcn_exp2f(ssv[j] * LOG2E - mm);
            se += e;
            const float4* vv = (const float4*)&Vb[g][ks][jj][0];
            fma4(a0, e, vv[0]); fma4(a1, e, vv[1]);
            int tw = ks * 25 + jj;
            int roww = (tw < 56) ? tw : tw - 19;
            float4 ve0 = *(const float4*)&rel[roww * 12 + 4];  // L1-resident
            float4 ve1 = *(const float4*)&rel[roww * 12 + 8];
            fma4(a2, e, ve0); fma4(a3, e, ve1);
        }
        bsb[b * 2400 + g * 300 + u * 75 + k * 25 + i] =
            m + __builtin_amdgcn_logf(se) * LN2;
        const float rinv = 1.0f / se;
        const float r2 = 0.1f * rinv;            // F_GV1
        a0.x *= rinv; a0.y *= rinv; a0.z *= rinv; a0.w *= rinv;
        a1.x *= rinv; a1.y *= rinv; a1.z *= rinv; a1.w *= rinv;
        a2.x *= r2;   a2.y *= r2;   a2.z *= r2;   a2.w *= r2;
        a3.x *= r2;   a3.y *= r2;   a3.z *= r2;   a3.w *= r2;
        float* rp = Rb + b * 38400 + 4800 * g + 1200 * u + 400 * k + 16 * i;
        ((float4*)rp)[0] = a0;
        ((float4*)rp)[1] = a1;
        ((float4*)rp)[2] = a2;
        ((float4*)rp)[3] = a3;
    }
}

// ---------------- K45: channel l2norm + pair-sum + unsort + hash softmax
//                        + transposed FP32 store ----------------
__global__ __launch_bounds__(256) void k45_post(
        const float* __restrict__ Rb, const float* __restrict__ bsb,
        const int* __restrict__ idx_buf, float* __restrict__ out) {
    __shared__ float D[300];
    __shared__ float bsn[300];
    __shared__ float retU[224][64];
    __shared__ float bsU[224];
    __shared__ int idxL[224];
    const int b = blockIdx.x, tid = threadIdx.x;
    const int n = b / 56, w = b % 56;
    const float* R = Rb + b * 38400;
    if (tid < 224) idxL[tid] = idx_buf[b * 224 + tid];
    for (int r = tid; r < 300; r += 256) {
        float s = 0.f;
        for (int c = 0; c < 128; ++c) { float v = R[c * 300 + r]; s += v * v; }
        D[r] = fmaxf(sqrtf(s), EPSN);
    }
    for (int idx = tid; idx < 300; idx += 256) {
        int u = idx / 75, t = idx % 75;
        float s2 = 0.f, sum = 0.f;
        #pragma unroll
        for (int g = 0; g < 8; ++g) {
            float v = bsb[b * 2400 + g * 300 + u * 75 + t];
            s2 += v * v; sum += v;
        }
        bsn[idx] = sum / fmaxf(sqrtf(s2), EPSN);
    }
    __syncthreads();
    for (int idx = tid; idx < 224 * 64; idx += 256) {
        int p = idx >> 6, o = idx & 63;
        int u3 = p / 56, t = p % 56;
        int k3 = t / 25, i3 = t % 25;
        int q0 = 9600 * u3 + 3200 * k3 + 128 * i3 + 2 * o;
        float2 rv = *(const float2*)&R[q0];
        float val = rv.x / D[q0 % 300] + rv.y / D[(q0 + 1) % 300];
        int r = idxL[p];
        retU[r][o] = val;
        if (o == 0) bsU[r] = bsn[u3 * 75 + t];
    }
    __syncthreads();
    for (int idx = tid; idx < 56 * 64; idx += 256) {
        int h = idx >> 6, o = idx & 63;
        float b0 = bsU[h], b1 = bsU[56 + h], b2 = bsU[112 + h], b3 = bsU[168 + h];
        float m = fmaxf(fmaxf(b0, b1), fmaxf(b2, b3));
        float e0 = __builtin_amdgcn_exp2f((b0 - m) * LOG2E);
        float e1 = __builtin_amdgcn_exp2f((b1 - m) * LOG2E);
        float e2 = __builtin_amdgcn_exp2f((b2 - m) * LOG2E);
        float e3 = __builtin_amdgcn_exp2f((b3 - m) * LOG2E);
        float ps = e0 + e1 + e2 + e3;
        float val = (retU[h][o] * e0 + retU[56 + h][o] * e1 +
                     retU[112 + h][o] * e2 + retU[168 + h][o] * e3) / ps;
        out[((n * 64 + o) * 56 + h) * 56 + w] = val;   // (n,o,h,w)
    }
}

extern "C" void kernel_launch(void* const* d_in, const int* in_sizes, int n_in,
                              void* d_out, int out_size, void* d_ws, size_t ws_size,
                              hipStream_t stream) {
    (void)in_sizes; (void)n_in; (void)out_size; (void)ws_size;
    const float* x     = (const float*)d_in[0];
    const float* cw    = (const float*)d_in[1];
    const float* gamma = (const float*)d_in[2];
    const float* beta  = (const float*)d_in[3];
    const float* rel   = (const float*)d_in[4];
    const float* rot   = (const float*)d_in[5];
    float* ws  = (float*)d_ws;
    float* qkv = ws;
    float* bsb = ws + 602112;
    float* Rb  = ws + 870912;
    int*   idx = (int*)(ws + 5171712);

    k12_qkv_sort<<<112, 256, 0, stream>>>(x, cw, gamma, beta, rot, qkv, idx);
    k3_attn<<<dim3(112, 4, 3), 256, 0, stream>>>(qkv, idx, rel, Rb, bsb);
    k45_post<<<112, 256, 0, stream>>>(Rb, bsb, idx, (float*)d_out);
}